// Round 5
// baseline (241.389 us; speedup 1.0000x reference)
//
#include <hip/hip_runtime.h>
#include <stdint.h>

#define NN 4096
#define FF 256
#define HH 4
#define DD 64
#define NEG 0.2f

#define ITILE 32               // 2 sub-tiles of 16 rows per wave
#define NSLICE 8
#define JRANGE (NN / NSLICE)   // 512
#define CJ 128                 // j's per stage
#define NSTG (JRANGE / CJ)     // 4
#define LROW 132               // 128 + 4 pad floats (2-way-free reads)

typedef __attribute__((ext_vector_type(8))) short short8;
typedef __attribute__((ext_vector_type(4))) float f32x4;

#define LOG2E 1.4426950408889634f

__device__ __forceinline__ uint16_t bf16_rh(float f) {
    uint32_t u = __float_as_uint(f);
    return (uint16_t)((u + 0x8000u) >> 16);
}
__device__ __forceinline__ uint32_t pk2(float a, float b) {
    uint32_t u0 = __float_as_uint(a) + 0x8000u;
    uint32_t u1 = __float_as_uint(b) + 0x8000u;
    return (u0 >> 16) | (u1 & 0xffff0000u);
}
__device__ __forceinline__ uint32_t enc_key(float f) {
    uint32_t u = __float_as_uint(f);
    return (u & 0x80000000u) ? ~u : (u | 0x80000000u);
}
__device__ __forceinline__ float dec_key(uint32_t k) {
    uint32_t u = (k & 0x80000000u) ? (k & 0x7fffffffu) : ~k;
    return __uint_as_float(u);
}

// ---- fused: h=x@W^T (MFMA, fp32 in, cvt in-flight) + s,t + H_T + gmax ------
__global__ __launch_bounds__(256) void proj_fused(
    const float* __restrict__ x, const float* __restrict__ W,
    const float* __restrict__ a_src, const float* __restrict__ a_dst,
    uint16_t* __restrict__ H_T, float* __restrict__ s,
    float* __restrict__ T_T, uint32_t* __restrict__ gkey) {
    const int tid = threadIdx.x;
    const int w = tid >> 6, l = tid & 63;
    const int m = l & 15, q = l >> 4;           // C: col=m, row=q*4+reg
    const int i0 = blockIdx.x * 16;
    f32x4 acc[4];
#pragma unroll
    for (int n = 0; n < 4; n++)
#pragma unroll
        for (int r = 0; r < 4; r++) acc[n][r] = 0.f;
    const float* xrow = x + (size_t)(i0 + m) * FF + q * 8;
    const float* wrow = W + (size_t)(w * 64 + m) * FF + q * 8;
#pragma unroll
    for (int k0 = 0; k0 < FF; k0 += 32) {
        float4 xa = *(const float4*)(xrow + k0);
        float4 xb = *(const float4*)(xrow + k0 + 4);
        union { uint32_t u[4]; short8 v; } af;
        af.u[0] = pk2(xa.x, xa.y); af.u[1] = pk2(xa.z, xa.w);
        af.u[2] = pk2(xb.x, xb.y); af.u[3] = pk2(xb.z, xb.w);
#pragma unroll
        for (int n = 0; n < 4; n++) {
            float4 wa = *(const float4*)(wrow + (size_t)n * 16 * FF + k0);
            float4 wb = *(const float4*)(wrow + (size_t)n * 16 * FF + k0 + 4);
            union { uint32_t u[4]; short8 v; } bf;
            bf.u[0] = pk2(wa.x, wa.y); bf.u[1] = pk2(wa.z, wa.w);
            bf.u[2] = pk2(wb.x, wb.y); bf.u[3] = pk2(wb.z, wb.w);
            acc[n] = __builtin_amdgcn_mfma_f32_16x16x32_bf16(af.v, bf.v, acc[n], 0, 0, 0);
        }
    }
#pragma unroll
    for (int n = 0; n < 4; n++) {
        ushort4 o;
        o.x = bf16_rh(acc[n][0]); o.y = bf16_rh(acc[n][1]);
        o.z = bf16_rh(acc[n][2]); o.w = bf16_rh(acc[n][3]);
        *(ushort4*)(H_T + (size_t)(w * 64 + n * 16 + m) * NN + i0 + q * 4) = o;
    }
    float ps[4] = {0.f, 0.f, 0.f, 0.f}, pt[4] = {0.f, 0.f, 0.f, 0.f};
#pragma unroll
    for (int n = 0; n < 4; n++) {
        float av = a_src[w * 64 + n * 16 + m];
        float dv = a_dst[w * 64 + n * 16 + m];
#pragma unroll
        for (int r = 0; r < 4; r++) {
            ps[r] = fmaf(acc[n][r], av, ps[r]);
            pt[r] = fmaf(acc[n][r], dv, pt[r]);
        }
    }
#pragma unroll
    for (int off = 1; off < 16; off <<= 1) {
#pragma unroll
        for (int r = 0; r < 4; r++) {
            ps[r] += __shfl_xor(ps[r], off, 64);
            pt[r] += __shfl_xor(pt[r], off, 64);
        }
    }
    if (m < 4) {
        int i = i0 + q * 4 + m;
        s[(size_t)i * HH + w] = ps[m];
        T_T[(size_t)w * NN + i] = pt[m];
    }
    float tm = fmaxf(fmaxf(pt[0], pt[1]), fmaxf(pt[2], pt[3]));
    tm = fmaxf(tm, __shfl_xor(tm, 16, 64));
    tm = fmaxf(tm, __shfl_xor(tm, 32, 64));
    if (l == 0) atomicMax(&gkey[w], enc_key(tm));
}

// ---- fused scores -> exp -> P (A-frag regs) -> MFMA PV ---------------------
// Block: 32 i x 512 j. Wave = head. Two 16-row sub-tiles share every B-frag
// load (2x fewer scattered H_T loads). adj staged via REGISTER prefetch at
// distance one full stage, ds_write after compute -> the compiler's
// vmcnt(0)-at-barrier never drains a fresh load. One barrier per 128-j stage.
__global__ __launch_bounds__(256, 4) void gat_main(
    const float* __restrict__ adj, const uint16_t* __restrict__ H_T,
    const float* __restrict__ s, const float* __restrict__ T_T,
    const uint32_t* __restrict__ gkey, float* __restrict__ pden,
    uint16_t* __restrict__ part) {
    __shared__ __align__(16) float adj_s[2][ITILE * LROW];   // 33.8 KB
    const int tid = threadIdx.x;
    const int w = tid >> 6, l = tid & 63;
    const int m = l & 15, q = l >> 4;           // A: row=m, k=q*8+j
    const int i0 = blockIdx.x * ITILE;
    const int jb = blockIdx.y * JRANGE;

    // staging map: float4 index f = tid + c*256 -> row f>>5, col4 f&31
    const int srow = tid >> 5, scol = (tid & 31) * 4;
    const float* gsrc = adj + (size_t)(i0 + srow) * NN + jb + scol;
    const int lws = srow * LROW + scol;

    // per-sub softmax constants (fold s_i, LOG2E, shift into 2 FMA consts)
    const float gm = dec_key(gkey[w]);
    float c1[2], c2[2];
#pragma unroll
    for (int sb = 0; sb < 2; sb++) {
        float sS = s[(size_t)(i0 + sb * 16 + m) * HH + w];
        float xM = sS + gm;
        float ML = fmaxf(xM, NEG * xM);
        float nMLL = -ML * LOG2E;
        c1[sb] = fmaf(sS, LOG2E, nMLL);
        c2[sb] = fmaf(sS, NEG * LOG2E, nMLL);
    }
    float den[2] = {0.f, 0.f};
    f32x4 acc[2][4];
#pragma unroll
    for (int sb = 0; sb < 2; sb++)
#pragma unroll
        for (int n = 0; n < 4; n++)
#pragma unroll
            for (int r = 0; r < 4; r++) acc[sb][n][r] = 0.f;
    const float* trow = T_T + (size_t)w * NN;
    const uint16_t* brow = H_T + (size_t)(w * 64 + m) * NN;

    float4 pr[4];
#pragma unroll
    for (int c = 0; c < 4; c++) pr[c] = *(const float4*)(gsrc + (size_t)((c * 256 + tid) >> 5) * NN + ((c * 256) & 31 ? 0 : 0));  // placeholder, fixed below
    // NOTE: f = tid + c*256 -> row = f>>5 varies with c; recompute properly:
#pragma unroll
    for (int c = 0; c < 4; c++) {
        int f = tid + c * 256;
        pr[c] = *(const float4*)(adj + (size_t)(i0 + (f >> 5)) * NN + jb + (f & 31) * 4);
    }
#pragma unroll
    for (int c = 0; c < 4; c++) {
        int f = tid + c * 256;
        *(float4*)&adj_s[0][(f >> 5) * LROW + (f & 31) * 4] = pr[c];
    }
    __syncthreads();
#pragma unroll
    for (int c = 0; c < 4; c++) {   // prefetch stage 1
        int f = tid + c * 256;
        pr[c] = *(const float4*)(adj + (size_t)(i0 + (f >> 5)) * NN + jb + CJ + (f & 31) * 4);
    }

    int buf = 0;
    for (int st = 0; st < NSTG; st++) {
        const float* lb = &adj_s[buf][0];
        const int jc = jb + st * CJ;
#pragma unroll
        for (int win = 0; win < 4; win++) {
            const int jg = jc + win * 32 + q * 8;
            float4 t0 = *(const float4*)(trow + jg);
            float4 t1 = *(const float4*)(trow + jg + 4);
            float tt[8] = {t0.x, t0.y, t0.z, t0.w, t1.x, t1.y, t1.z, t1.w};
            short8 bf[4];
#pragma unroll
            for (int n = 0; n < 4; n++)
                bf[n] = *(const short8*)(brow + (size_t)n * 16 * NN + jg);
#pragma unroll
            for (int sb = 0; sb < 2; sb++) {
                const float* lrow = lb + (sb * 16 + m) * LROW + win * 32 + q * 8;
                float4 a0 = *(const float4*)(lrow);
                float4 a1 = *(const float4*)(lrow + 4);
                float av[8] = {a0.x, a0.y, a0.z, a0.w, a1.x, a1.y, a1.z, a1.w};
                uint32_t pk[4];
                float d0 = 0.f;
#pragma unroll
                for (int jj = 0; jj < 8; jj += 2) {
                    float e0 = exp2f(fmaf(tt[jj], LOG2E, c1[sb]) >
                                     fmaf(tt[jj], NEG * LOG2E, c2[sb])
                                         ? fmaf(tt[jj], LOG2E, c1[sb])
                                         : fmaf(tt[jj], NEG * LOG2E, c2[sb]));
                    float e1 = exp2f(fmaf(tt[jj + 1], LOG2E, c1[sb]) >
                                     fmaf(tt[jj + 1], NEG * LOG2E, c2[sb])
                                         ? fmaf(tt[jj + 1], LOG2E, c1[sb])
                                         : fmaf(tt[jj + 1], NEG * LOG2E, c2[sb]));
                    e0 = (av[jj] > 0.f) ? e0 : 0.f;
                    e1 = (av[jj + 1] > 0.f) ? e1 : 0.f;
                    d0 += e0 + e1;
                    pk[jj >> 1] = pk2(e0 * av[jj], e1 * av[jj + 1]);
                }
                den[sb] += d0;
                union { uint32_t u[4]; short8 v; } afu;
#pragma unroll
                for (int c = 0; c < 4; c++) afu.u[c] = pk[c];
#pragma unroll
                for (int n = 0; n < 4; n++)
                    acc[sb][n] = __builtin_amdgcn_mfma_f32_16x16x32_bf16(
                        afu.v, bf[n], acc[sb][n], 0, 0, 0);
            }
        }
        if (st + 1 < NSTG) {
#pragma unroll
            for (int c = 0; c < 4; c++) {   // ds_write prefetched stage st+1
                int f = tid + c * 256;
                *(float4*)&adj_s[buf ^ 1][(f >> 5) * LROW + (f & 31) * 4] = pr[c];
            }
            __syncthreads();
            if (st + 2 < NSTG) {            // prefetch st+2 AFTER the barrier
#pragma unroll
                for (int c = 0; c < 4; c++) {
                    int f = tid + c * 256;
                    pr[c] = *(const float4*)(adj + (size_t)(i0 + (f >> 5)) * NN +
                                             jb + (st + 2) * CJ + (f & 31) * 4);
                }
            }
        }
        buf ^= 1;
    }
#pragma unroll
    for (int sb = 0; sb < 2; sb++) {
        float d = den[sb];
        d += __shfl_xor(d, 16, 64);
        d += __shfl_xor(d, 32, 64);
        if (l < 16) atomicAdd(&pden[(size_t)(i0 + sb * 16 + m) * HH + w], d);
    }
    uint16_t* pbase = part + (size_t)blockIdx.y * NN * FF;
#pragma unroll
    for (int sb = 0; sb < 2; sb++)
#pragma unroll
        for (int n = 0; n < 4; n++)
#pragma unroll
            for (int r = 0; r < 4; r++)
                pbase[(size_t)(i0 + sb * 16 + q * 4 + r) * FF + w * 64 + n * 16 + m] =
                    bf16_rh(acc[sb][n][r]);
}

// ---- sum slice partials, divide by denom -----------------------------------
__global__ __launch_bounds__(256) void finalize(const uint16_t* __restrict__ part,
                                                const float* __restrict__ pden,
                                                float* __restrict__ out) {
    const int i = blockIdx.x, f = threadIdx.x;
    float sum = 0.f;
#pragma unroll
    for (int sl = 0; sl < NSLICE; sl++) {
        uint16_t v = part[(size_t)sl * NN * FF + (size_t)i * FF + f];
        sum += __uint_as_float(((uint32_t)v) << 16);
    }
    float d = pden[(size_t)i * HH + (f >> 6)];
    out[(size_t)i * FF + f] = (d > 0.f) ? sum / d : 0.f;
}

extern "C" void kernel_launch(void* const* d_in, const int* in_sizes, int n_in,
                              void* d_out, int out_size, void* d_ws, size_t ws_size,
                              hipStream_t stream) {
    const float* x     = (const float*)d_in[0];
    const float* adj   = (const float*)d_in[1];
    const float* W     = (const float*)d_in[2];
    const float* a_src = (const float*)d_in[3];
    const float* a_dst = (const float*)d_in[4];
    float* out = (float*)d_out;

    char* ws = (char*)d_ws;
    uint16_t* H_T  = (uint16_t*)ws;                        // 2 MB
    uint16_t* part = (uint16_t*)(ws + (2u << 20));         // 16 MB
    float*    s    = (float*)(ws + (18u << 20));           // 64 KB
    float*    T_T  = s + (size_t)NN * HH;                  // 64 KB
    float*    pden = T_T + (size_t)NN * HH;                // 64 KB
    uint32_t* gkey = (uint32_t*)(pden + (size_t)NN * HH);  // 16 B

    hipMemsetAsync(pden, 0, (size_t)NN * HH * sizeof(float) + 16, stream);
    proj_fused<<<NN / 16, 256, 0, stream>>>(x, W, a_src, a_dst, H_T, s, T_T, gkey);
    gat_main<<<dim3(NN / ITILE, NSLICE), 256, 0, stream>>>(adj, H_T, s, T_T, gkey, pden, part);
    finalize<<<NN, 256, 0, stream>>>(part, pden, out);
}

// Round 6
// 192.968 us; speedup vs baseline: 1.2509x; 1.2509x over previous
//
#include <hip/hip_runtime.h>
#include <stdint.h>

#define NN 4096
#define FF 256
#define HH 4
#define DD 64
#define NEG 0.2f

#define ITILE 16
#define NSLICE 8
#define JRANGE (NN / NSLICE)   // 512
#define CJ 64                  // j's per LDS stage
#define NSTG (JRANGE / CJ)     // 8

typedef __attribute__((ext_vector_type(8))) short short8;
typedef __attribute__((ext_vector_type(4))) float f32x4;

#define LOG2E 1.4426950408889634f
#define NEGL2E (0.2f * 1.4426950408889634f)

__device__ __forceinline__ uint16_t bf16_rh(float f) {
    uint32_t u = __float_as_uint(f);
    return (uint16_t)((u + 0x8000u) >> 16);
}
__device__ __forceinline__ uint32_t pk2(float a, float b) {
    uint32_t u0 = __float_as_uint(a) + 0x8000u;
    uint32_t u1 = __float_as_uint(b) + 0x8000u;
    return (u0 >> 16) | (u1 & 0xffff0000u);
}
__device__ __forceinline__ uint32_t enc_key(float f) {
    uint32_t u = __float_as_uint(f);
    return (u & 0x80000000u) ? ~u : (u | 0x80000000u);
}
__device__ __forceinline__ float dec_key(uint32_t k) {
    uint32_t u = (k & 0x80000000u) ? (k & 0x7fffffffu) : ~k;
    return __uint_as_float(u);
}

// ---- fused: h=x@W^T (MFMA, fp32 in, cvt in-flight) + s,t + H_T + gmax ------
__global__ __launch_bounds__(256) void proj_fused(
    const float* __restrict__ x, const float* __restrict__ W,
    const float* __restrict__ a_src, const float* __restrict__ a_dst,
    uint16_t* __restrict__ H_T, float* __restrict__ s,
    float* __restrict__ T_T, uint32_t* __restrict__ gkey) {
    const int tid = threadIdx.x;
    const int w = tid >> 6, l = tid & 63;
    const int m = l & 15, q = l >> 4;           // C: col=m, row=q*4+reg
    const int i0 = blockIdx.x * 16;
    f32x4 acc[4];
#pragma unroll
    for (int n = 0; n < 4; n++)
#pragma unroll
        for (int r = 0; r < 4; r++) acc[n][r] = 0.f;
    const float* xrow = x + (size_t)(i0 + m) * FF + q * 8;
    const float* wrow = W + (size_t)(w * 64 + m) * FF + q * 8;
#pragma unroll
    for (int k0 = 0; k0 < FF; k0 += 32) {
        float4 xa = *(const float4*)(xrow + k0);
        float4 xb = *(const float4*)(xrow + k0 + 4);
        union { uint32_t u[4]; short8 v; } af;
        af.u[0] = pk2(xa.x, xa.y); af.u[1] = pk2(xa.z, xa.w);
        af.u[2] = pk2(xb.x, xb.y); af.u[3] = pk2(xb.z, xb.w);
#pragma unroll
        for (int n = 0; n < 4; n++) {
            float4 wa = *(const float4*)(wrow + (size_t)n * 16 * FF + k0);
            float4 wb = *(const float4*)(wrow + (size_t)n * 16 * FF + k0 + 4);
            union { uint32_t u[4]; short8 v; } bf;
            bf.u[0] = pk2(wa.x, wa.y); bf.u[1] = pk2(wa.z, wa.w);
            bf.u[2] = pk2(wb.x, wb.y); bf.u[3] = pk2(wb.z, wb.w);
            acc[n] = __builtin_amdgcn_mfma_f32_16x16x32_bf16(af.v, bf.v, acc[n], 0, 0, 0);
        }
    }
#pragma unroll
    for (int n = 0; n < 4; n++) {
        ushort4 o;
        o.x = bf16_rh(acc[n][0]); o.y = bf16_rh(acc[n][1]);
        o.z = bf16_rh(acc[n][2]); o.w = bf16_rh(acc[n][3]);
        *(ushort4*)(H_T + (size_t)(w * 64 + n * 16 + m) * NN + i0 + q * 4) = o;
    }
    float ps[4] = {0.f, 0.f, 0.f, 0.f}, pt[4] = {0.f, 0.f, 0.f, 0.f};
#pragma unroll
    for (int n = 0; n < 4; n++) {
        float av = a_src[w * 64 + n * 16 + m];
        float dv = a_dst[w * 64 + n * 16 + m];
#pragma unroll
        for (int r = 0; r < 4; r++) {
            ps[r] = fmaf(acc[n][r], av, ps[r]);
            pt[r] = fmaf(acc[n][r], dv, pt[r]);
        }
    }
#pragma unroll
    for (int off = 1; off < 16; off <<= 1) {
#pragma unroll
        for (int r = 0; r < 4; r++) {
            ps[r] += __shfl_xor(ps[r], off, 64);
            pt[r] += __shfl_xor(pt[r], off, 64);
        }
    }
    if (m < 4) {
        int i = i0 + q * 4 + m;
        s[(size_t)i * HH + w] = ps[m];
        T_T[(size_t)w * NN + i] = pt[m];
    }
    float tm = fmaxf(fmaxf(pt[0], pt[1]), fmaxf(pt[2], pt[3]));
    tm = fmaxf(tm, __shfl_xor(tm, 16, 64));
    tm = fmaxf(tm, __shfl_xor(tm, 32, 64));
    if (l == 0) atomicMax(&gkey[w], enc_key(tm));
}

// ---- fused scores -> exp -> P (A-frag regs) -> MFMA PV ---------------------
// Block: 16 i x 512 j; wave = head. adj: coalesced float4 -> transposed
// [j][i+1] LDS tile (writes & reads both <=2-way = free), double-buffered,
// ONE barrier per 64-j stage; adj prefetch issued after the barrier and
// ds_written after compute (full stage in flight). t/H_T fragments software-
// pipelined one 32-j window ahead (ping-pong) to hide scattered-L2 latency.
__global__ __launch_bounds__(256) void gat_main(
    const float* __restrict__ adj, const uint16_t* __restrict__ H_T,
    const float* __restrict__ s, const float* __restrict__ T_T,
    const uint32_t* __restrict__ gkey, float* __restrict__ pden,
    uint16_t* __restrict__ part) {
    __shared__ float adj_s[2][CJ][ITILE + 1];   // 8.7 KB
    const int tid = threadIdx.x;
    const int w = tid >> 6, l = tid & 63;
    const int m = l & 15, q = l >> 4;           // A: row=m, k=q*8+j
    const int i0 = blockIdx.x * ITILE;
    const int jb = blockIdx.y * JRANGE;

    // staging map: thread -> row frow, j-quad fc4 (4 rows x 256B per wave)
    const int frow = tid >> 4, fc4 = tid & 15;
    const float* gstage = adj + (size_t)(i0 + frow) * NN + jb + fc4 * 4;

    const float gm = dec_key(gkey[w]);
    const float sS = s[(size_t)(i0 + m) * HH + w];
    const float xM = sS + gm;
    const float ML = fmaxf(xM, NEG * xM);       // lrelu monotone upper bound
    const float nMLL = -ML * LOG2E;
    const float c1 = fmaf(sS, LOG2E, nMLL);     // arg(pos) = t*LOG2E + c1
    const float c2 = fmaf(sS, NEGL2E, nMLL);    // arg(neg) = t*0.2*LOG2E + c2

    float den = 0.f;
    f32x4 acc[4];
#pragma unroll
    for (int n = 0; n < 4; n++)
#pragma unroll
        for (int r = 0; r < 4; r++) acc[n][r] = 0.f;
    const float* trow = T_T + (size_t)w * NN;
    const uint16_t* brow = H_T + (size_t)(w * 64 + m) * NN;

    struct Frag { float4 t0, t1; short8 bf[4]; };
    Frag fr[2];
#define LOAD_FRAG(F, JG)                                                     \
    do {                                                                     \
        (F).t0 = *(const float4*)(trow + (JG));                              \
        (F).t1 = *(const float4*)(trow + (JG) + 4);                          \
        _Pragma("unroll") for (int n_ = 0; n_ < 4; n_++)                     \
            (F).bf[n_] = *(const short8*)(brow + (size_t)n_ * 16 * NN + (JG)); \
    } while (0)

    // prologue: stage 0 adj -> LDS, window-0 frags
    {
        float4 v0 = *(const float4*)(gstage);
        adj_s[0][fc4 * 4 + 0][frow] = v0.x;
        adj_s[0][fc4 * 4 + 1][frow] = v0.y;
        adj_s[0][fc4 * 4 + 2][frow] = v0.z;
        adj_s[0][fc4 * 4 + 3][frow] = v0.w;
    }
    LOAD_FRAG(fr[0], jb + q * 8);

    int buf = 0;
    for (int st = 0; st < NSTG; st++) {
        __syncthreads();                        // stage(st) LDS writes visible
        float4 v;
        if (st + 1 < NSTG)                      // adj prefetch: in flight all stage
            v = *(const float4*)(gstage + (st + 1) * CJ);
        const float(*lb)[ITILE + 1] = adj_s[buf];
#pragma unroll
        for (int win = 0; win < 2; win++) {
            if (win == 0) {                     // frag prefetch one window ahead
                LOAD_FRAG(fr[1], jb + (st * 2 + 1) * 32 + q * 8);
            } else if (st + 1 < NSTG) {
                LOAD_FRAG(fr[0], jb + (st * 2 + 2) * 32 + q * 8);
            }
            const Frag& cf = fr[win];
            const int rbase = win * 32 + q * 8;
            float tt[8] = {cf.t0.x, cf.t0.y, cf.t0.z, cf.t0.w,
                           cf.t1.x, cf.t1.y, cf.t1.z, cf.t1.w};
            uint32_t pk[4];
#pragma unroll
            for (int jj = 0; jj < 8; jj += 2) {
                float av0 = lb[rbase + jj][m];
                float av1 = lb[rbase + jj + 1][m];
                float a0 = fmaxf(fmaf(tt[jj], LOG2E, c1), fmaf(tt[jj], NEGL2E, c2));
                float a1 = fmaxf(fmaf(tt[jj + 1], LOG2E, c1), fmaf(tt[jj + 1], NEGL2E, c2));
                a0 = (av0 > 0.f) ? a0 : -1e38f;
                a1 = (av1 > 0.f) ? a1 : -1e38f;
                float e0 = exp2f(a0), e1 = exp2f(a1);
                den += e0 + e1;
                pk[jj >> 1] = pk2(e0 * av0, e1 * av1);
            }
            union { uint32_t u[4]; short8 v; } afu;
#pragma unroll
            for (int c = 0; c < 4; c++) afu.u[c] = pk[c];
#pragma unroll
            for (int n = 0; n < 4; n++)
                acc[n] = __builtin_amdgcn_mfma_f32_16x16x32_bf16(afu.v, cf.bf[n],
                                                                 acc[n], 0, 0, 0);
        }
        if (st + 1 < NSTG) {                    // write prefetched stage
            float(*aw)[ITILE + 1] = adj_s[buf ^ 1];
            aw[fc4 * 4 + 0][frow] = v.x;
            aw[fc4 * 4 + 1][frow] = v.y;
            aw[fc4 * 4 + 2][frow] = v.z;
            aw[fc4 * 4 + 3][frow] = v.w;
        }
        buf ^= 1;
    }
    den += __shfl_xor(den, 16, 64);             // reduce over q (same i=m)
    den += __shfl_xor(den, 32, 64);
    if (l < 16) atomicAdd(&pden[(size_t)(i0 + m) * HH + w], den);
    uint16_t* pbase = part + (size_t)blockIdx.y * NN * FF;
#pragma unroll
    for (int n = 0; n < 4; n++)
#pragma unroll
        for (int r = 0; r < 4; r++)
            pbase[(size_t)(i0 + q * 4 + r) * FF + w * 64 + n * 16 + m] =
                bf16_rh(acc[n][r]);
#undef LOAD_FRAG
}

// ---- sum slice partials, divide by denom -----------------------------------
__global__ __launch_bounds__(256) void finalize(const uint16_t* __restrict__ part,
                                                const float* __restrict__ pden,
                                                float* __restrict__ out) {
    const int i = blockIdx.x, f = threadIdx.x;
    float sum = 0.f;
#pragma unroll
    for (int sl = 0; sl < NSLICE; sl++) {
        uint16_t v = part[(size_t)sl * NN * FF + (size_t)i * FF + f];
        sum += __uint_as_float(((uint32_t)v) << 16);
    }
    float d = pden[(size_t)i * HH + (f >> 6)];
    out[(size_t)i * FF + f] = (d > 0.f) ? sum / d : 0.f;
}

extern "C" void kernel_launch(void* const* d_in, const int* in_sizes, int n_in,
                              void* d_out, int out_size, void* d_ws, size_t ws_size,
                              hipStream_t stream) {
    const float* x     = (const float*)d_in[0];
    const float* adj   = (const float*)d_in[1];
    const float* W     = (const float*)d_in[2];
    const float* a_src = (const float*)d_in[3];
    const float* a_dst = (const float*)d_in[4];
    float* out = (float*)d_out;

    char* ws = (char*)d_ws;
    uint16_t* H_T  = (uint16_t*)ws;                        // 2 MB
    uint16_t* part = (uint16_t*)(ws + (2u << 20));         // 16 MB
    float*    s    = (float*)(ws + (18u << 20));           // 64 KB
    float*    T_T  = s + (size_t)NN * HH;                  // 64 KB
    float*    pden = T_T + (size_t)NN * HH;                // 64 KB
    uint32_t* gkey = (uint32_t*)(pden + (size_t)NN * HH);  // 16 B

    hipMemsetAsync(pden, 0, (size_t)NN * HH * sizeof(float) + 16, stream);
    proj_fused<<<NN / 16, 256, 0, stream>>>(x, W, a_src, a_dst, H_T, s, T_T, gkey);
    gat_main<<<dim3(NN / ITILE, NSLICE), 256, 0, stream>>>(adj, H_T, s, T_T, gkey, pden, part);
    finalize<<<NN, 256, 0, stream>>>(part, pden, out);
}